// Round 5
// baseline (470.665 us; speedup 1.0000x reference)
//
#include <hip/hip_runtime.h>

typedef unsigned short ushort_t;

#define B_SZ 8192
#define D_SZ 1024
#define U_SZ 512
#define F_SZ 4
#define E_SZ 4
#define T_SZ 2

typedef __attribute__((ext_vector_type(8))) short bf16x8;     // 8 bf16 = 4 VGPRs (MFMA A/B frag)
typedef __attribute__((ext_vector_type(4))) float f32x4;      // MFMA C/D frag
typedef __attribute__((ext_vector_type(8))) unsigned short u16x8;

__device__ __forceinline__ unsigned short f2bf(float f) {
  union { float f; unsigned int u; } v; v.f = f;
  unsigned int r = v.u + 0x7FFFu + ((v.u >> 16) & 1u);  // RNE; inputs are finite normals
  return (unsigned short)(r >> 16);
}
__device__ __forceinline__ float bf2f(unsigned short h) {
  union { unsigned int u; float f; } v; v.u = ((unsigned int)h) << 16;
  return v.f;
}

// async global->LDS, 16B per lane; LDS dest = wave-uniform base + lane*16
__device__ __forceinline__ void gload_lds16(const void* g, void* l) {
  __builtin_amdgcn_global_load_lds(
      (const __attribute__((address_space(1))) unsigned int*)g,
      (__attribute__((address_space(3))) unsigned int*)l, 16, 0, 0);
}

// ================= fused prep: conv_x | conv_w | gates | patterns =================
// block role by blockIdx.x: [0,4096) conv_x, [4096,6272) conv_w, [6272,7296) gates,
// [7296,7328) pattern+histogram. Shared 40KB smem union.
__global__ __launch_bounds__(256) void prep_k(
    const float* __restrict__ x, const float* __restrict__ Wc,
    const float* __restrict__ We, const float* __restrict__ Wg,
    const float* __restrict__ bg,
    ushort_t* __restrict__ xbf, ushort_t* __restrict__ wbf,
    float* __restrict__ gates, unsigned int* __restrict__ pat,
    unsigned int* __restrict__ rowinfo, int* __restrict__ blockhist) {
  __shared__ __align__(16) char smem[40960];
  const int bid = blockIdx.x;
  const int t = threadIdx.x;

  if (bid < 4096) {
    // ---- conv_x: fp32 -> bf16, 8 elems/thread ----
    const size_t i = ((size_t)bid * 256 + t) * 8;
    const float4 a = *(const float4*)(x + i);
    const float4 c = *(const float4*)(x + i + 4);
    u16x8 o;
    o[0] = f2bf(a.x); o[1] = f2bf(a.y); o[2] = f2bf(a.z); o[3] = f2bf(a.w);
    o[4] = f2bf(c.x); o[5] = f2bf(c.y); o[6] = f2bf(c.z); o[7] = f2bf(c.w);
    *(u16x8*)(xbf + i) = o;
  } else if (bid < 6272) {
    // ---- conv_w: transpose+convert 17 [D][U] fp32 -> [U][D] bf16, 64x64 tiles ----
    const int blk = bid - 4096;
    const int midx = blk >> 7;
    const int tid = blk & 127;
    const int trow = (tid >> 3) * 64;
    const int tcol = (tid & 7) * 64;
    const float* src = (midx == 0) ? Wc : (We + (size_t)(midx - 1) * D_SZ * U_SZ);
    ushort_t* dst = wbf + (size_t)midx * U_SZ * D_SZ;
    float (*tile)[69] = (float(*)[69])smem;   // 64*69*4 = 17664 B
    const int r0 = t >> 2;
    const int cseg = (t & 3) * 16;
#pragma unroll
    for (int j = 0; j < 4; ++j) {
      const float4 v = *(const float4*)(src + (size_t)(trow + r0) * U_SZ + tcol + cseg + j * 4);
      tile[r0][cseg + j * 4 + 0] = v.x;
      tile[r0][cseg + j * 4 + 1] = v.y;
      tile[r0][cseg + j * 4 + 2] = v.z;
      tile[r0][cseg + j * 4 + 3] = v.w;
    }
    __syncthreads();
    const int u = t >> 2;
    const int d0 = (t & 3) * 16;
#pragma unroll
    for (int h = 0; h < 2; ++h) {
      u16x8 ov;
#pragma unroll
      for (int k = 0; k < 8; ++k) ov[k] = f2bf(tile[d0 + h * 8 + k][u]);
      *(u16x8*)(dst + (size_t)(tcol + u) * D_SZ + trow + d0 + h * 8) = ov;
    }
  } else if (bid < 7296) {
    // ---- gates: per-task softmax over F+1, 8 rows/block ----
    const int gb = bid - 6272;
    float* wgT = (float*)smem;                // 10*1024*4 = 40960 B
#pragma unroll
    for (int j = 0; j < 40; ++j) {
      const int i = j * 256 + t;
      const int t2 = i / 5120;
      const int rem = i - t2 * 5120;
      const int d = rem / 5;
      const int g = rem - d * 5;
      wgT[(t2 * 5 + g) * 1024 + d] = Wg[i];
    }
    __syncthreads();
    const int lane = t & 63;
    const int w = t >> 6;
#pragma unroll
    for (int rr = 0; rr < 2; ++rr) {
      const int b = gb * 8 + w * 2 + rr;
      const float* xr = x + (size_t)b * D_SZ;
      float p[10];
#pragma unroll
      for (int j = 0; j < 10; ++j) p[j] = 0.f;
#pragma unroll
      for (int i = 0; i < 4; ++i) {
        const int d0 = i * 256 + lane * 4;
        const float4 xv = *(const float4*)(xr + d0);
#pragma unroll
        for (int g = 0; g < 10; ++g) {
          const float4 wv = *(const float4*)(wgT + g * 1024 + d0);
          p[g] += xv.x * wv.x + xv.y * wv.y + xv.z * wv.z + xv.w * wv.w;
        }
      }
#pragma unroll
      for (int off = 32; off > 0; off >>= 1)
#pragma unroll
        for (int j = 0; j < 10; ++j) p[j] += __shfl_xor(p[j], off);
      float l[10];
#pragma unroll
      for (int j = 0; j < 10; ++j) l[j] = p[j] + bg[j];
      const float mx0 = fmaxf(fmaxf(fmaxf(l[0], l[1]), fmaxf(l[2], l[3])), l[4]);
      const float mx1 = fmaxf(fmaxf(fmaxf(l[5], l[6]), fmaxf(l[7], l[8])), l[9]);
      float ev[10]; float s0 = 0.f, s1 = 0.f;
#pragma unroll
      for (int g = 0; g < 5; ++g) { ev[g] = expf(l[g] - mx0); s0 += ev[g]; }
#pragma unroll
      for (int g = 5; g < 10; ++g) { ev[g] = expf(l[g] - mx1); s1 += ev[g]; }
      if (lane < 5) gates[(size_t)b * 10 + lane] = ev[lane] / s0;
      else if (lane < 10) gates[(size_t)b * 10 + lane] = ev[lane] / s1;
    }
  } else {
    // ---- patterns + per-block LDS histogram (LDS atomics only) ----
    const int pb = bid - 7296;                // 0..31, 256 rows each
    int* hist = (int*)smem;                   // 64 ints
    if (t < 64) hist[t] = 0;
    __syncthreads();
    const int b = pb * 256 + t;
    const float4 a = *(const float4*)(x + (size_t)b * D_SZ);
    const float4 c = *(const float4*)(x + (size_t)b * D_SZ + 4);
    const float v0 = x[(size_t)b * D_SZ + 8];
    const float v1 = x[(size_t)b * D_SZ + 9];
    int pp[4];
    pp[0] = (int)(a.x > 0.f) | ((int)(a.y > 0.f) << 1) |
            ((int)(a.z > 0.f) << 2) | ((int)(a.w > 0.f) << 3);
    pp[1] = (int)(c.x > 0.f) | ((int)(c.y > 0.f) << 1) |
            ((int)(c.z > 0.f) << 2) | ((int)(c.w > 0.f) << 3);
    const float LO[4] = {-1e10f, -0.5f, 0.f, 0.5f};
    const float HI[4] = {-0.5f, 0.f, 0.5f, 1e10f};
    pp[2] = 0; pp[3] = 0;
#pragma unroll
    for (int j = 0; j < 4; ++j) {
      if ((v0 > LO[j]) && (v0 <= HI[j])) pp[2] = 1 << j;
      if ((v1 > LO[j]) && (v1 <= HI[j])) pp[3] = 1 << j;
    }
    pat[b] = (unsigned int)(pp[0] | (pp[1] << 4) | (pp[2] << 8) | (pp[3] << 12));
    unsigned int info = 0;
#pragma unroll
    for (int f = 0; f < 4; ++f) {
      if (pp[f]) {
        const int lp = atomicAdd(&hist[f * 16 + pp[f]], 1);   // LDS atomic
        info |= (unsigned int)lp << (8 * f);
      }
    }
    rowinfo[b] = info;
    __syncthreads();
    if (t < 64) blockhist[pb * 64 + t] = hist[t];
  }
}

// ======= scan block histograms + directory + scatter row indices (1 block) =======
__global__ __launch_bounds__(1024) void scanscat_k(
    const int* __restrict__ blockhist, const unsigned int* __restrict__ pat,
    const unsigned int* __restrict__ rowinfo,
    int* __restrict__ rowidx, int* __restrict__ cnt,
    int* __restrict__ dir, int* __restrict__ ntiles) {
  __shared__ int sbase[32 * 64];   // per-block bases
  const int t = threadIdx.x;
  if (t < 64) {
    int run = 0;
    for (int blk = 0; blk < 32; ++blk) {
      sbase[blk * 64 + t] = run;
      run += blockhist[blk * 64 + t];
    }
    cnt[t] = run;
  }
  __syncthreads();
  if (t < 4) {
    const int f = t;
    int idx = 0;
    for (int pop = 4; pop >= 1; --pop) {
      for (int p = 1; p < 16; ++p) {
        if (__popc(p) != pop) continue;
        int n = 0;
        for (int blk = 0; blk < 32; ++blk) n += blockhist[blk * 64 + f * 16 + p];
        const int nt = (n + 127) >> 7;
        for (int k = 0; k < nt; ++k) dir[f * 80 + idx++] = p | (k << 8);
      }
    }
    ntiles[f] = idx;
  }
  // scatter: 8 rows per thread
#pragma unroll
  for (int it = 0; it < 8; ++it) {
    const int b = it * 1024 + t;
    const unsigned int pv = pat[b];
    const unsigned int info = rowinfo[b];
    const int blk = b >> 8;
#pragma unroll
    for (int f = 0; f < 4; ++f) {
      const int p = (int)((pv >> (4 * f)) & 15u);
      if (p) {
        const int pos = sbase[blk * 64 + f * 16 + p] + (int)((info >> (8 * f)) & 255u);
        rowidx[((size_t)(f * 16 + p)) * B_SZ + pos] = b;
      }
    }
  }
}

// ================= pattern-grouped gathered bf16 MFMA GEMM =================
// 512 threads, tile m=128 x n=256 (2 u-chunks -> halved A multiplicity vs 4).
// grid (80,5,2); z-siblings are 400 blocks apart == 0 mod 8 -> same XCD, L2-share A.
// y<4: field y, dir-entry tile, K-passes = popcount(pattern), relu-accumulate.
// y==4: common expert, direct rows, slots 0..63.
__global__ __launch_bounds__(512, 4) void gemm2(
    const ushort_t* __restrict__ xbf, const ushort_t* __restrict__ wbf,
    const int* __restrict__ rowidx, const int* __restrict__ cnt,
    const int* __restrict__ dir, const int* __restrict__ ntiles,
    const float* __restrict__ bc, const float* __restrict__ be,
    ushort_t* __restrict__ common, ushort_t* __restrict__ fout) {
  __shared__ ushort_t Ash[128 * 64];   // 16 KB
  __shared__ ushort_t Bsh[256 * 64];   // 32 KB
  __shared__ int ridx[128];

  const int t = threadIdx.x;
  const int lane = t & 63;
  const int w = t >> 6;          // 0..7: wave grid 2(m) x 4(n), 64x64 per wave
  const int wm = w >> 2;
  const int wn = w & 3;
  const int quad = lane >> 4;
  const int l16 = lane & 15;
  const int f = blockIdx.y;      // 0..3 fields, 4 = common
  const int slot = blockIdx.x;
  const int u0 = blockIdx.z * 256;
  const bool isCommon = (f == 4);

  int p = 0, nrows = 128;
  if (isCommon) {
    if (slot >= 64) return;
    if (t < 128) ridx[t] = slot * 128 + t;
  } else {
    if (slot >= ntiles[f]) return;
    const int entry = dir[f * 80 + slot];
    p = entry & 15;
    const int tw = entry >> 8;
    const int n = cnt[f * 16 + p];
    const int rbase = tw * 128;
    nrows = min(128, n - rbase);
    if (t < 128) {
      const int rr = rbase + ((t < nrows) ? t : 0);   // clamp pads to first row
      ridx[t] = rowidx[((size_t)f * 16 + p) * B_SZ + rr];
    }
  }
  __syncthreads();

  // staging maps (XOR chunk swizzle): A 1024 chunks / 2 per thread, B 2048 / 4
  size_t aoff[2]; int aldsoff[2];
#pragma unroll
  for (int i = 0; i < 2; ++i) {
    const int c = (w * 2 + i) * 64 + lane;
    const int r = c >> 3;
    const int gc = (c & 7) ^ (r & 7);
    aoff[i] = (size_t)ridx[r] * D_SZ + gc * 8;
    aldsoff[i] = (w * 2 + i) * 1024;
  }
  int boff[4]; int bldsoff[4];
#pragma unroll
  for (int i = 0; i < 4; ++i) {
    const int c = (w * 4 + i) * 64 + lane;
    const int r = c >> 3;                    // 0..255
    const int gc = (c & 7) ^ (r & 7);
    boff[i] = r * D_SZ + gc * 8;
    bldsoff[i] = (w * 4 + i) * 1024;
  }

  int rowA[4], rowB[4];
#pragma unroll
  for (int i = 0; i < 4; ++i) {
    rowA[i] = wm * 64 + i * 16 + l16;        // 0..127
    rowB[i] = wn * 64 + i * 16 + l16;        // 0..255
  }
  int sw[2];
  sw[0] = ((quad) ^ (l16 & 7)) * 8;
  sw[1] = ((4 + quad) ^ (l16 & 7)) * 8;

  int elist[4]; int ne = 0;
  if (isCommon) { elist[0] = 0; ne = 1; }
  else {
#pragma unroll
    for (int e = 0; e < 4; ++e)
      if (p & (1 << e)) elist[ne++] = e;
  }

  const f32x4 fzero = {0.f, 0.f, 0.f, 0.f};
  f32x4 facc[4][4];
#pragma unroll
  for (int mi = 0; mi < 4; ++mi)
#pragma unroll
    for (int ni = 0; ni < 4; ++ni) facc[mi][ni] = fzero;

  for (int ei = 0; ei < ne; ++ei) {
    const int midx = isCommon ? 0 : (1 + f * 4 + elist[ei]);
    const ushort_t* wbase = wbf + (size_t)midx * (U_SZ * D_SZ) + (size_t)u0 * D_SZ;
    f32x4 acc[4][4];
#pragma unroll
    for (int mi = 0; mi < 4; ++mi)
#pragma unroll
      for (int ni = 0; ni < 4; ++ni) acc[mi][ni] = fzero;

    for (int k0 = 0; k0 < D_SZ; k0 += 64) {
#pragma unroll
      for (int i = 0; i < 2; ++i)
        gload_lds16(xbf + aoff[i] + k0, (char*)Ash + aldsoff[i]);
#pragma unroll
      for (int i = 0; i < 4; ++i)
        gload_lds16(wbase + boff[i] + k0, (char*)Bsh + bldsoff[i]);
      __syncthreads();
#pragma unroll
      for (int qs = 0; qs < 2; ++qs) {
        bf16x8 av[4], bv[4];
#pragma unroll
        for (int mi = 0; mi < 4; ++mi)
          av[mi] = *(const bf16x8*)(Ash + rowA[mi] * 64 + sw[qs]);
#pragma unroll
        for (int ni = 0; ni < 4; ++ni)
          bv[ni] = *(const bf16x8*)(Bsh + rowB[ni] * 64 + sw[qs]);
#pragma unroll
        for (int mi = 0; mi < 4; ++mi)
#pragma unroll
          for (int ni = 0; ni < 4; ++ni)
            acc[mi][ni] = __builtin_amdgcn_mfma_f32_16x16x32_bf16(av[mi], bv[ni],
                                                                  acc[mi][ni], 0, 0, 0);
      }
      __syncthreads();
    }

    if (isCommon) {
#pragma unroll
      for (int mi = 0; mi < 4; ++mi) {
        const int rowb = slot * 128 + wm * 64 + mi * 16 + quad * 4;  // C/D row = quad*4+reg
#pragma unroll
        for (int ni = 0; ni < 4; ++ni) {
          const int u = u0 + wn * 64 + ni * 16 + l16;                // C/D col = lane&15
          const float bcv = bc[u];
#pragma unroll
          for (int r = 0; r < 4; ++r) {
            const float v = fmaxf(acc[mi][ni][r] + bcv, 0.f);
            common[(size_t)(rowb + r) * U_SZ + u] = f2bf(v);
          }
        }
      }
    } else {
      const float* bevp = be + (size_t)(f * 4 + elist[ei]) * U_SZ;
#pragma unroll
      for (int ni = 0; ni < 4; ++ni) {
        const int u = u0 + wn * 64 + ni * 16 + l16;
        const float bev = bevp[u];
#pragma unroll
        for (int mi = 0; mi < 4; ++mi)
#pragma unroll
          for (int r = 0; r < 4; ++r)
            facc[mi][ni][r] += fmaxf(acc[mi][ni][r] + bev, 0.f);
      }
    }
  }

  if (!isCommon) {
#pragma unroll
    for (int mi = 0; mi < 4; ++mi) {
      const int rowl = wm * 64 + mi * 16 + quad * 4;
#pragma unroll
      for (int r = 0; r < 4; ++r) {
        if (rowl + r < nrows) {
          const int brow = ridx[rowl + r];
#pragma unroll
          for (int ni = 0; ni < 4; ++ni) {
            const int u = u0 + wn * 64 + ni * 16 + l16;
            fout[((size_t)brow * F_SZ + f) * U_SZ + u] = f2bf(facc[mi][ni][r]);
          }
        }
      }
    }
  }
}

// ---------------- stage 2: att/upd scalars, blend, gate mix ----------------
__global__ __launch_bounds__(256) void stage2_k(
    const ushort_t* __restrict__ common, const ushort_t* __restrict__ fout,
    const unsigned int* __restrict__ pat, const float* __restrict__ gates,
    const float* __restrict__ Wa, const float* __restrict__ ba,
    const float* __restrict__ Wu, const float* __restrict__ bu,
    float* __restrict__ out) {
  const int b = blockIdx.x;
  const int t = threadIdx.x;
  const int lane = t & 63;
  const int w = t >> 6;
  const unsigned int pv = pat[b];

  const float c0 = bf2f(common[(size_t)b * U_SZ + t]);
  const float c1 = bf2f(common[(size_t)b * U_SZ + 256 + t]);
  float fo0[4], fo1[4];
#pragma unroll
  for (int f = 0; f < 4; ++f) {
    const bool act = ((pv >> (4 * f)) & 15u) != 0u;   // pattern 0 -> field_out is 0
    fo0[f] = act ? bf2f(fout[((size_t)b * F_SZ + f) * U_SZ + t]) : 0.f;
    fo1[f] = act ? bf2f(fout[((size_t)b * F_SZ + f) * U_SZ + 256 + t]) : 0.f;
  }
  float pa[4], pu[4];
#pragma unroll
  for (int f = 0; f < 4; ++f) {
    const float* wa = Wa + f * 1024;   // cat = [common(0..511), field(512..1023)]
    pa[f] = c0 * wa[t] + c1 * wa[256 + t] + fo0[f] * wa[512 + t] + fo1[f] * wa[768 + t];
    const float* wu = Wu + f * 1024;
    pu[f] = c0 * wu[t] + c1 * wu[256 + t] + fo0[f] * wu[512 + t] + fo1[f] * wu[768 + t];
  }
#pragma unroll
  for (int off = 32; off > 0; off >>= 1) {
#pragma unroll
    for (int f = 0; f < 4; ++f) {
      pa[f] += __shfl_xor(pa[f], off);
      pu[f] += __shfl_xor(pu[f], off);
    }
  }
  __shared__ float redA[4][4];
  __shared__ float redU[4][4];
  __shared__ float gsh[10];
  if (lane == 0) {
#pragma unroll
    for (int f = 0; f < 4; ++f) { redA[w][f] = pa[f]; redU[w][f] = pu[f]; }
  }
  if (t < 10) gsh[t] = gates[(size_t)b * 10 + t];
  __syncthreads();
  float ff0[4], ff1[4];
#pragma unroll
  for (int f = 0; f < 4; ++f) {
    const float sa = redA[0][f] + redA[1][f] + redA[2][f] + redA[3][f] + ba[f];
    const float su = redU[0][f] + redU[1][f] + redU[2][f] + redU[3][f] + bu[f];
    const float att = 1.f / (1.f + expf(-sa));
    const float upd = 1.f / (1.f + expf(-su));
    ff0[f] = upd * (att * fo0[f]) + (1.f - upd) * c0;
    ff1[f] = upd * (att * fo1[f]) + (1.f - upd) * c1;
  }
#pragma unroll
  for (int t2 = 0; t2 < 2; ++t2) {
    float v0 = gsh[t2 * 5] * c0;
    float v1 = gsh[t2 * 5] * c1;
#pragma unroll
    for (int f = 0; f < 4; ++f) {
      v0 += gsh[t2 * 5 + 1 + f] * ff0[f];
      v1 += gsh[t2 * 5 + 1 + f] * ff1[f];
    }
    out[((size_t)b * T_SZ + t2) * U_SZ + t] = v0;
    out[((size_t)b * T_SZ + t2) * U_SZ + 256 + t] = v1;
  }
}

// ---------------- launch ----------------
extern "C" void kernel_launch(void* const* d_in, const int* in_sizes, int n_in,
                              void* d_out, int out_size, void* d_ws, size_t ws_size,
                              hipStream_t stream) {
  (void)in_sizes; (void)n_in; (void)out_size; (void)ws_size;
  const float* x  = (const float*)d_in[0];
  const float* Wc = (const float*)d_in[1];
  const float* bc = (const float*)d_in[2];
  const float* We = (const float*)d_in[3];
  const float* be = (const float*)d_in[4];
  const float* Wg = (const float*)d_in[5];
  const float* bg = (const float*)d_in[6];
  const float* Wa = (const float*)d_in[7];
  const float* ba = (const float*)d_in[8];
  const float* Wu = (const float*)d_in[9];
  const float* bu = (const float*)d_in[10];
  float* out = (float*)d_out;
  char* ws = (char*)d_ws;

  // ws layout (bytes), all 16B aligned
  const size_t O_XBF    = 0;                                        // B*D*2
  const size_t O_WBF    = O_XBF + (size_t)B_SZ * D_SZ * 2;          // 17*U*D*2
  const size_t O_PAT    = O_WBF + (size_t)17 * U_SZ * D_SZ * 2;     // B*4
  const size_t O_ROWIDX = O_PAT + (size_t)B_SZ * 4;                 // 4*16*B*4
  const size_t O_CNT    = O_ROWIDX + (size_t)4 * 16 * B_SZ * 4;     // 64*4
  const size_t O_DIR    = O_CNT + 256;                              // 4*80*4
  const size_t O_NT     = O_DIR + 1280;                             // 4*4 (pad 16)
  const size_t O_GATES  = O_NT + 16;                                // B*10*4
  const size_t O_COMMON = O_GATES + (size_t)B_SZ * 10 * 4;          // B*U*2
  const size_t O_FOUT   = O_COMMON + (size_t)B_SZ * U_SZ * 2;       // B*F*U*2
  const size_t O_RINFO  = O_FOUT + (size_t)B_SZ * F_SZ * U_SZ * 2;  // B*4
  const size_t O_BHIST  = O_RINFO + (size_t)B_SZ * 4;               // 32*64*4

  ushort_t* xbf     = (ushort_t*)(ws + O_XBF);
  ushort_t* wbf     = (ushort_t*)(ws + O_WBF);
  unsigned int* patp= (unsigned int*)(ws + O_PAT);
  int*      rowidxp = (int*)(ws + O_ROWIDX);
  int*      cntp    = (int*)(ws + O_CNT);
  int*      dirp    = (int*)(ws + O_DIR);
  int*      ntp     = (int*)(ws + O_NT);
  float*    gatesp  = (float*)(ws + O_GATES);
  ushort_t* commonp = (ushort_t*)(ws + O_COMMON);
  ushort_t* foutp   = (ushort_t*)(ws + O_FOUT);
  unsigned int* rinfop = (unsigned int*)(ws + O_RINFO);
  int*      bhistp  = (int*)(ws + O_BHIST);

  prep_k<<<dim3(7328), dim3(256), 0, stream>>>(x, Wc, We, Wg, bg, xbf, wbf,
                                               gatesp, patp, rinfop, bhistp);
  scanscat_k<<<dim3(1), dim3(1024), 0, stream>>>(bhistp, patp, rinfop,
                                                 rowidxp, cntp, dirp, ntp);
  gemm2<<<dim3(80, 5, 2), dim3(512), 0, stream>>>(xbf, wbf, rowidxp, cntp, dirp, ntp,
                                                  bc, be, commonp, foutp);
  stage2_k<<<dim3(8192), dim3(256), 0, stream>>>(commonp, foutp, patp, gatesp,
                                                 Wa, ba, Wu, bu, out);
}

// Round 6
// 281.374 us; speedup vs baseline: 1.6727x; 1.6727x over previous
//
#include <hip/hip_runtime.h>

typedef unsigned short ushort_t;

#define B_SZ 8192
#define D_SZ 1024
#define U_SZ 512
#define F_SZ 4
#define E_SZ 4
#define T_SZ 2

typedef __attribute__((ext_vector_type(8))) short bf16x8;     // 8 bf16 = 4 VGPRs (MFMA A/B frag)
typedef __attribute__((ext_vector_type(4))) float f32x4;      // MFMA C/D frag
typedef __attribute__((ext_vector_type(8))) unsigned short u16x8;

__device__ __forceinline__ unsigned short f2bf(float f) {
  union { float f; unsigned int u; } v; v.f = f;
  unsigned int r = v.u + 0x7FFFu + ((v.u >> 16) & 1u);  // RNE; inputs are finite normals
  return (unsigned short)(r >> 16);
}
__device__ __forceinline__ float bf2f(unsigned short h) {
  union { unsigned int u; float f; } v; v.u = ((unsigned int)h) << 16;
  return v.f;
}

// async global->LDS, 16B per lane; LDS dest = wave-uniform base + lane*16
__device__ __forceinline__ void gload_lds16(const void* g, void* l) {
  __builtin_amdgcn_global_load_lds(
      (const __attribute__((address_space(1))) unsigned int*)g,
      (__attribute__((address_space(3))) unsigned int*)l, 16, 0, 0);
}

// ============ prep: conv_x | conv_w | Wg-transpose | patterns ============
// bid <4096 conv_x; <6272 conv_w; ==6272 WgT; >=6273 patterns (32 blocks).
// smem 17664 B -> high occupancy for the streaming roles.
__global__ __launch_bounds__(256) void prep_k(
    const float* __restrict__ x, const float* __restrict__ Wc,
    const float* __restrict__ We, const float* __restrict__ Wg,
    ushort_t* __restrict__ xbf, ushort_t* __restrict__ wbf,
    ushort_t* __restrict__ wgbf, unsigned int* __restrict__ pat,
    unsigned int* __restrict__ rowinfo, int* __restrict__ blockhist) {
  __shared__ __align__(16) char smem[17664];
  const int bid = blockIdx.x;
  const int t = threadIdx.x;

  if (bid < 4096) {
    // ---- conv_x ----
    const size_t i = ((size_t)bid * 256 + t) * 8;
    const float4 a = *(const float4*)(x + i);
    const float4 c = *(const float4*)(x + i + 4);
    u16x8 o;
    o[0] = f2bf(a.x); o[1] = f2bf(a.y); o[2] = f2bf(a.z); o[3] = f2bf(a.w);
    o[4] = f2bf(c.x); o[5] = f2bf(c.y); o[6] = f2bf(c.z); o[7] = f2bf(c.w);
    *(u16x8*)(xbf + i) = o;
  } else if (bid < 6272) {
    // ---- conv_w: 17 matrices [D][U] fp32 -> [U][D] bf16, 64x64 tiles ----
    const int blk = bid - 4096;
    const int midx = blk >> 7;
    const int tid = blk & 127;
    const int trow = (tid >> 3) * 64;
    const int tcol = (tid & 7) * 64;
    const float* src = (midx == 0) ? Wc : (We + (size_t)(midx - 1) * D_SZ * U_SZ);
    ushort_t* dst = wbf + (size_t)midx * U_SZ * D_SZ;
    float (*tile)[69] = (float(*)[69])smem;
    const int r0 = t >> 2;
    const int cseg = (t & 3) * 16;
#pragma unroll
    for (int j = 0; j < 4; ++j) {
      const float4 v = *(const float4*)(src + (size_t)(trow + r0) * U_SZ + tcol + cseg + j * 4);
      tile[r0][cseg + j * 4 + 0] = v.x;
      tile[r0][cseg + j * 4 + 1] = v.y;
      tile[r0][cseg + j * 4 + 2] = v.z;
      tile[r0][cseg + j * 4 + 3] = v.w;
    }
    __syncthreads();
    const int u = t >> 2;
    const int d0 = (t & 3) * 16;
#pragma unroll
    for (int h = 0; h < 2; ++h) {
      u16x8 ov;
#pragma unroll
      for (int k = 0; k < 8; ++k) ov[k] = f2bf(tile[d0 + h * 8 + k][u]);
      *(u16x8*)(dst + (size_t)(tcol + u) * D_SZ + trow + d0 + h * 8) = ov;
    }
  } else if (bid == 6272) {
    // ---- WgT: Wg[t2][d][g] fp32 -> wgbf[16][1024] bf16 (rows 10..15 zero) ----
#pragma unroll
    for (int j = 0; j < 40; ++j) {
      const int i = j * 256 + t;            // coalesced
      const int t2 = i / 5120;
      const int rem = i - t2 * 5120;
      const int d = rem / 5;
      const int g = rem - d * 5;
      wgbf[(t2 * 5 + g) * 1024 + d] = f2bf(Wg[i]);
    }
#pragma unroll
    for (int j = 0; j < 24; ++j)
      wgbf[10 * 1024 + j * 256 + t] = 0;
  } else {
    // ---- patterns + per-block LDS histogram ----
    const int pb = bid - 6273;              // 0..31, 256 rows each
    int* hist = (int*)smem;
    if (t < 64) hist[t] = 0;
    __syncthreads();
    const int b = pb * 256 + t;
    const float4 a = *(const float4*)(x + (size_t)b * D_SZ);
    const float4 c = *(const float4*)(x + (size_t)b * D_SZ + 4);
    const float v0 = x[(size_t)b * D_SZ + 8];
    const float v1 = x[(size_t)b * D_SZ + 9];
    int pp[4];
    pp[0] = (int)(a.x > 0.f) | ((int)(a.y > 0.f) << 1) |
            ((int)(a.z > 0.f) << 2) | ((int)(a.w > 0.f) << 3);
    pp[1] = (int)(c.x > 0.f) | ((int)(c.y > 0.f) << 1) |
            ((int)(c.z > 0.f) << 2) | ((int)(c.w > 0.f) << 3);
    const float LO[4] = {-1e10f, -0.5f, 0.f, 0.5f};
    const float HI[4] = {-0.5f, 0.f, 0.5f, 1e10f};
    pp[2] = 0; pp[3] = 0;
#pragma unroll
    for (int j = 0; j < 4; ++j) {
      if ((v0 > LO[j]) && (v0 <= HI[j])) pp[2] = 1 << j;
      if ((v1 > LO[j]) && (v1 <= HI[j])) pp[3] = 1 << j;
    }
    pat[b] = (unsigned int)(pp[0] | (pp[1] << 4) | (pp[2] << 8) | (pp[3] << 12));
    unsigned int info = 0;
#pragma unroll
    for (int f = 0; f < 4; ++f) {
      if (pp[f]) {
        const int lp = atomicAdd(&hist[f * 16 + pp[f]], 1);   // LDS atomic
        info |= (unsigned int)lp << (8 * f);
      }
    }
    rowinfo[b] = info;
    __syncthreads();
    if (t < 64) blockhist[pb * 64 + t] = hist[t];
  }
}

// ===== scan histograms + directory + scatter (1 block, LDS-resident) =====
__global__ __launch_bounds__(1024) void scanscat_k(
    const int* __restrict__ blockhist, const unsigned int* __restrict__ pat,
    const unsigned int* __restrict__ rowinfo,
    int* __restrict__ rowidx, int* __restrict__ cnt,
    int* __restrict__ dir, int* __restrict__ ntiles) {
  __shared__ int shist[32 * 64];
  __shared__ int scnt[64];
  const int t = threadIdx.x;
  shist[t] = blockhist[t];
  shist[t + 1024] = blockhist[t + 1024];
  __syncthreads();
  if (t < 64) {                       // in-place exclusive scan, column t
    int run = 0;
    for (int blk = 0; blk < 32; ++blk) {
      const int v = shist[blk * 64 + t];
      shist[blk * 64 + t] = run;
      run += v;
    }
    scnt[t] = run;
    cnt[t] = run;
  }
  __syncthreads();
  if (t < 4) {
    const int f = t;
    int idx = 0;
    for (int pop = 4; pop >= 1; --pop) {
      for (int p = 1; p < 16; ++p) {
        if (__popc(p) != pop) continue;
        const int n = scnt[f * 16 + p];
        const int nt = (n + 127) >> 7;
        for (int k = 0; k < nt; ++k) dir[f * 80 + idx++] = p | (k << 8);
      }
    }
    ntiles[f] = idx;
  }
#pragma unroll
  for (int it = 0; it < 8; ++it) {
    const int b = it * 1024 + t;
    const unsigned int pv = pat[b];
    const unsigned int info = rowinfo[b];
    const int blk = b >> 8;
#pragma unroll
    for (int f = 0; f < 4; ++f) {
      const int p = (int)((pv >> (4 * f)) & 15u);
      if (p) {
        const int pos = shist[blk * 64 + f * 16 + p] + (int)((info >> (8 * f)) & 255u);
        rowidx[((size_t)(f * 16 + p)) * B_SZ + pos] = b;
      }
    }
  }
}

// ================= pattern-grouped gathered bf16 MFMA GEMM + gates =================
// 1D grid, uc FASTEST-varying so u-chunk siblings are co-resident and share the A
// panel via L2/L3. id: uc=id&3, s=id>>2; s<320: field s/80, slot s%80;
// s<384: common (slot s-320); else gates GEMM (slot s-384, uc 0 only):
// logits = xbf @ wgbf^T (n-tile 16, 10 valid) + in-block softmax -> gates.
__global__ __launch_bounds__(256, 2) void gemm2(
    const ushort_t* __restrict__ xbf, const ushort_t* __restrict__ wbf,
    const ushort_t* __restrict__ wgbf, const float* __restrict__ bg,
    const int* __restrict__ rowidx, const int* __restrict__ cnt,
    const int* __restrict__ dir, const int* __restrict__ ntiles,
    const float* __restrict__ bc, const float* __restrict__ be,
    ushort_t* __restrict__ common, ushort_t* __restrict__ fout,
    float* __restrict__ gates) {
  __shared__ ushort_t Ash[128 * 64];
  __shared__ ushort_t Bsh[128 * 64];
  __shared__ int ridx[128];

  const int t = threadIdx.x;
  const int lane = t & 63;
  const int w = t >> 6;
  const int wm = w >> 1;
  const int wn = w & 1;
  const int quad = lane >> 4;
  const int l16 = lane & 15;

  const int id = blockIdx.x;
  const int uc = id & 3;
  const int s = id >> 2;
  int g, slot;
  if (s < 320) { g = s / 80; slot = s - g * 80; }
  else if (s < 384) { g = 4; slot = s - 320; }
  else { g = 5; slot = s - 384; }
  const int u0 = uc * 128;

  // ---------------- gates GEMM branch ----------------
  if (g == 5) {
    if (uc != 0) return;
    if (t < 128) ridx[t] = slot * 128 + t;
    __syncthreads();
    size_t aoff[4]; int aldso[4];
#pragma unroll
    for (int i = 0; i < 4; ++i) {
      const int c = (w * 4 + i) * 64 + lane;
      const int r = c >> 3;
      const int gc = (c & 7) ^ (r & 7);
      aoff[i] = (size_t)ridx[r] * D_SZ + gc * 8;
      aldso[i] = (w * 4 + i) * 1024;
    }
    int bo = 0, bldso = 0;
    if (w < 2) {                       // 128 B-chunks (16 rows x 8)
      const int c = w * 64 + lane;
      const int r = c >> 3;
      const int gc = (c & 7) ^ (r & 7);
      bo = r * D_SZ + gc * 8;
      bldso = w * 1024;
    }
    int sw[2];
    sw[0] = ((quad) ^ (l16 & 7)) * 8;
    sw[1] = ((4 + quad) ^ (l16 & 7)) * 8;
    const f32x4 fzero = {0.f, 0.f, 0.f, 0.f};
    f32x4 acc[2];                      // wave w owns m-frags w*2, w*2+1
    acc[0] = fzero; acc[1] = fzero;
    for (int k0 = 0; k0 < D_SZ; k0 += 64) {
#pragma unroll
      for (int i = 0; i < 4; ++i)
        gload_lds16(xbf + aoff[i] + k0, (char*)Ash + aldso[i]);
      if (w < 2) gload_lds16(wgbf + bo + k0, (char*)Bsh + bldso);
      __syncthreads();
#pragma unroll
      for (int qs = 0; qs < 2; ++qs) {
        const bf16x8 bv = *(const bf16x8*)(Bsh + l16 * 64 + sw[qs]);
#pragma unroll
        for (int i = 0; i < 2; ++i) {
          const bf16x8 av = *(const bf16x8*)(Ash + (w * 32 + i * 16 + l16) * 64 + sw[qs]);
          acc[i] = __builtin_amdgcn_mfma_f32_16x16x32_bf16(av, bv, acc[i], 0, 0, 0);
        }
      }
      __syncthreads();
    }
    float* lsc = (float*)Ash;          // 128 x 16 logits
#pragma unroll
    for (int i = 0; i < 2; ++i)
#pragma unroll
      for (int r = 0; r < 4; ++r)
        lsc[(w * 32 + i * 16 + quad * 4 + r) * 16 + l16] = acc[i][r];
    __syncthreads();
    if (t < 128) {
      const int b = slot * 128 + t;
      float l[10];
#pragma unroll
      for (int k = 0; k < 10; ++k) l[k] = lsc[t * 16 + k] + bg[k];
      const float mx0 = fmaxf(fmaxf(fmaxf(l[0], l[1]), fmaxf(l[2], l[3])), l[4]);
      const float mx1 = fmaxf(fmaxf(fmaxf(l[5], l[6]), fmaxf(l[7], l[8])), l[9]);
      float ev[10]; float s0 = 0.f, s1 = 0.f;
#pragma unroll
      for (int k = 0; k < 5; ++k) { ev[k] = expf(l[k] - mx0); s0 += ev[k]; }
#pragma unroll
      for (int k = 5; k < 10; ++k) { ev[k] = expf(l[k] - mx1); s1 += ev[k]; }
      const float r0 = 1.f / s0, r1 = 1.f / s1;
#pragma unroll
      for (int k = 0; k < 5; ++k) gates[(size_t)b * 10 + k] = ev[k] * r0;
#pragma unroll
      for (int k = 5; k < 10; ++k) gates[(size_t)b * 10 + k] = ev[k] * r1;
    }
    return;
  }

  // ---------------- expert GEMM (field / common) ----------------
  const bool isCommon = (g == 4);
  int p = 0, nrows = 128;
  if (isCommon) {
    if (t < 128) ridx[t] = slot * 128 + t;
  } else {
    if (slot >= ntiles[g]) return;
    const int entry = dir[g * 80 + slot];
    p = entry & 15;
    const int tw = entry >> 8;
    const int n = cnt[g * 16 + p];
    const int rbase = tw * 128;
    nrows = min(128, n - rbase);
    if (t < 128) {
      const int rr = rbase + ((t < nrows) ? t : 0);
      ridx[t] = rowidx[((size_t)g * 16 + p) * B_SZ + rr];
    }
  }
  __syncthreads();

  size_t aoff[4]; int boff[4]; int ldso[4];
#pragma unroll
  for (int i = 0; i < 4; ++i) {
    const int c = (w * 4 + i) * 64 + lane;
    const int r = c >> 3;
    const int gc = (c & 7) ^ (r & 7);
    aoff[i] = (size_t)ridx[r] * D_SZ + gc * 8;
    boff[i] = r * D_SZ + gc * 8;
    ldso[i] = (w * 4 + i) * 1024;
  }
  int rowA[4], rowB[4];
#pragma unroll
  for (int i = 0; i < 4; ++i) {
    rowA[i] = wm * 64 + i * 16 + l16;
    rowB[i] = wn * 64 + i * 16 + l16;
  }
  int sw[2];
  sw[0] = ((quad) ^ (l16 & 7)) * 8;
  sw[1] = ((4 + quad) ^ (l16 & 7)) * 8;

  int elist[4]; int ne = 0;
  if (isCommon) { elist[0] = 0; ne = 1; }
  else {
#pragma unroll
    for (int e = 0; e < 4; ++e)
      if (p & (1 << e)) elist[ne++] = e;
  }

  const f32x4 fzero = {0.f, 0.f, 0.f, 0.f};
  f32x4 facc[4][4];
#pragma unroll
  for (int mi = 0; mi < 4; ++mi)
#pragma unroll
    for (int ni = 0; ni < 4; ++ni) facc[mi][ni] = fzero;

  for (int ei = 0; ei < ne; ++ei) {
    const int midx = isCommon ? 0 : (1 + g * 4 + elist[ei]);
    const ushort_t* wbase = wbf + (size_t)midx * (U_SZ * D_SZ) + (size_t)u0 * D_SZ;
    f32x4 acc[4][4];
#pragma unroll
    for (int mi = 0; mi < 4; ++mi)
#pragma unroll
      for (int ni = 0; ni < 4; ++ni) acc[mi][ni] = fzero;

    for (int k0 = 0; k0 < D_SZ; k0 += 64) {
#pragma unroll
      for (int i = 0; i < 4; ++i) {
        gload_lds16(xbf + aoff[i] + k0, (char*)Ash + ldso[i]);
        gload_lds16(wbase + boff[i] + k0, (char*)Bsh + ldso[i]);
      }
      __syncthreads();
#pragma unroll
      for (int qs = 0; qs < 2; ++qs) {
        bf16x8 av[4], bv[4];
#pragma unroll
        for (int mi = 0; mi < 4; ++mi)
          av[mi] = *(const bf16x8*)(Ash + rowA[mi] * 64 + sw[qs]);
#pragma unroll
        for (int ni = 0; ni < 4; ++ni)
          bv[ni] = *(const bf16x8*)(Bsh + rowB[ni] * 64 + sw[qs]);
#pragma unroll
        for (int mi = 0; mi < 4; ++mi)
#pragma unroll
          for (int ni = 0; ni < 4; ++ni)
            acc[mi][ni] = __builtin_amdgcn_mfma_f32_16x16x32_bf16(av[mi], bv[ni],
                                                                  acc[mi][ni], 0, 0, 0);
      }
      __syncthreads();
    }

    if (isCommon) {
#pragma unroll
      for (int mi = 0; mi < 4; ++mi) {
        const int rowb = slot * 128 + wm * 64 + mi * 16 + quad * 4;  // row = quad*4+reg
#pragma unroll
        for (int ni = 0; ni < 4; ++ni) {
          const int u = u0 + wn * 64 + ni * 16 + l16;                // col = lane&15
          const float bcv = bc[u];
#pragma unroll
          for (int r = 0; r < 4; ++r) {
            const float v = fmaxf(acc[mi][ni][r] + bcv, 0.f);
            common[(size_t)(rowb + r) * U_SZ + u] = f2bf(v);
          }
        }
      }
    } else {
      const float* bevp = be + (size_t)(g * 4 + elist[ei]) * U_SZ;
#pragma unroll
      for (int ni = 0; ni < 4; ++ni) {
        const int u = u0 + wn * 64 + ni * 16 + l16;
        const float bev = bevp[u];
#pragma unroll
        for (int mi = 0; mi < 4; ++mi)
#pragma unroll
          for (int r = 0; r < 4; ++r)
            facc[mi][ni][r] += fmaxf(acc[mi][ni][r] + bev, 0.f);
      }
    }
  }

  if (!isCommon) {
#pragma unroll
    for (int mi = 0; mi < 4; ++mi) {
      const int rowl = wm * 64 + mi * 16 + quad * 4;
#pragma unroll
      for (int r = 0; r < 4; ++r) {
        if (rowl + r < nrows) {
          const int brow = ridx[rowl + r];
#pragma unroll
          for (int ni = 0; ni < 4; ++ni) {
            const int u = u0 + wn * 64 + ni * 16 + l16;
            fout[((size_t)brow * F_SZ + g) * U_SZ + u] = f2bf(facc[mi][ni][r]);
          }
        }
      }
    }
  }
}

// ---------------- stage 2: one wave per row ----------------
__global__ __launch_bounds__(256) void stage2_k(
    const ushort_t* __restrict__ common, const ushort_t* __restrict__ fout,
    const unsigned int* __restrict__ pat, const float* __restrict__ gates,
    const float* __restrict__ Wa, const float* __restrict__ ba,
    const float* __restrict__ Wu, const float* __restrict__ bu,
    float* __restrict__ out) {
  const int t = threadIdx.x;
  const int lane = t & 63;
  const int w = t >> 6;
  const int b = blockIdx.x * 4 + w;
  const int ub = lane * 8;
  const unsigned int pv = pat[b];

  float cf[8];
  {
    const u16x8 cv = *(const u16x8*)(common + (size_t)b * U_SZ + ub);
#pragma unroll
    for (int j = 0; j < 8; ++j) cf[j] = bf2f(cv[j]);
  }
  float fo[4][8];
#pragma unroll
  for (int f = 0; f < 4; ++f) {
    const bool act = ((pv >> (4 * f)) & 15u) != 0u;
    const u16x8 fv = *(const u16x8*)(fout + ((size_t)b * F_SZ + f) * U_SZ + ub);
#pragma unroll
    for (int j = 0; j < 8; ++j) fo[f][j] = act ? bf2f(fv[j]) : 0.f;
  }
  float pa[4], pu[4];
#pragma unroll
  for (int f = 0; f < 4; ++f) {
    const float* wa = Wa + f * 1024;
    const float* wu = Wu + f * 1024;
    const float4 a0 = *(const float4*)(wa + ub);
    const float4 a1 = *(const float4*)(wa + ub + 4);
    const float4 a2 = *(const float4*)(wa + 512 + ub);
    const float4 a3 = *(const float4*)(wa + 512 + ub + 4);
    const float4 u0v = *(const float4*)(wu + ub);
    const float4 u1v = *(const float4*)(wu + ub + 4);
    const float4 u2v = *(const float4*)(wu + 512 + ub);
    const float4 u3v = *(const float4*)(wu + 512 + ub + 4);
    pa[f] = cf[0]*a0.x + cf[1]*a0.y + cf[2]*a0.z + cf[3]*a0.w
          + cf[4]*a1.x + cf[5]*a1.y + cf[6]*a1.z + cf[7]*a1.w
          + fo[f][0]*a2.x + fo[f][1]*a2.y + fo[f][2]*a2.z + fo[f][3]*a2.w
          + fo[f][4]*a3.x + fo[f][5]*a3.y + fo[f][6]*a3.z + fo[f][7]*a3.w;
    pu[f] = cf[0]*u0v.x + cf[1]*u0v.y + cf[2]*u0v.z + cf[3]*u0v.w
          + cf[4]*u1v.x + cf[5]*u1v.y + cf[6]*u1v.z + cf[7]*u1v.w
          + fo[f][0]*u2v.x + fo[f][1]*u2v.y + fo[f][2]*u2v.z + fo[f][3]*u2v.w
          + fo[f][4]*u3v.x + fo[f][5]*u3v.y + fo[f][6]*u3v.z + fo[f][7]*u3v.w;
  }
#pragma unroll
  for (int off = 32; off > 0; off >>= 1) {
#pragma unroll
    for (int f = 0; f < 4; ++f) {
      pa[f] += __shfl_xor(pa[f], off);
      pu[f] += __shfl_xor(pu[f], off);
    }
  }
  float gg[10];
#pragma unroll
  for (int k = 0; k < 10; ++k) gg[k] = gates[(size_t)b * 10 + k];  // same addr: broadcast
  float o0[8], o1[8];
#pragma unroll
  for (int j = 0; j < 8; ++j) { o0[j] = gg[0] * cf[j]; o1[j] = gg[5] * cf[j]; }
#pragma unroll
  for (int f = 0; f < 4; ++f) {
    const float att = 1.f / (1.f + expf(-(pa[f] + ba[f])));
    const float upd = 1.f / (1.f + expf(-(pu[f] + bu[f])));
    const float au = att * upd, cu = 1.f - upd;
#pragma unroll
    for (int j = 0; j < 8; ++j) {
      const float ff = au * fo[f][j] + cu * cf[j];
      o0[j] += gg[1 + f] * ff;
      o1[j] += gg[6 + f] * ff;
    }
  }
  float* op0 = out + ((size_t)b * T_SZ + 0) * U_SZ + ub;
  float* op1 = out + ((size_t)b * T_SZ + 1) * U_SZ + ub;
  *(float4*)(op0)     = make_float4(o0[0], o0[1], o0[2], o0[3]);
  *(float4*)(op0 + 4) = make_float4(o0[4], o0[5], o0[6], o0[7]);
  *(float4*)(op1)     = make_float4(o1[0], o1[1], o1[2], o1[3]);
  *(float4*)(op1 + 4) = make_float4(o1[4], o1[5], o1[6], o1[7]);
}

// ---------------- launch ----------------
extern "C" void kernel_launch(void* const* d_in, const int* in_sizes, int n_in,
                              void* d_out, int out_size, void* d_ws, size_t ws_size,
                              hipStream_t stream) {
  (void)in_sizes; (void)n_in; (void)out_size; (void)ws_size;
  const float* x  = (const float*)d_in[0];
  const float* Wc = (const float*)d_in[1];
  const float* bc = (const float*)d_in[2];
  const float* We = (const float*)d_in[3];
  const float* be = (const float*)d_in[4];
  const float* Wg = (const float*)d_in[5];
  const float* bg = (const float*)d_in[6];
  const float* Wa = (const float*)d_in[7];
  const float* ba = (const float*)d_in[8];
  const float* Wu = (const float*)d_in[9];
  const float* bu = (const float*)d_in[10];
  float* out = (float*)d_out;
  char* ws = (char*)d_ws;

  const size_t O_XBF    = 0;                                        // B*D*2
  const size_t O_WBF    = O_XBF + (size_t)B_SZ * D_SZ * 2;          // 17*U*D*2
  const size_t O_WGBF   = O_WBF + (size_t)17 * U_SZ * D_SZ * 2;     // 16*1024*2
  const size_t O_PAT    = O_WGBF + 16 * 1024 * 2;                   // B*4
  const size_t O_ROWIDX = O_PAT + (size_t)B_SZ * 4;                 // 4*16*B*4
  const size_t O_CNT    = O_ROWIDX + (size_t)4 * 16 * B_SZ * 4;     // 64*4
  const size_t O_DIR    = O_CNT + 256;                              // 4*80*4
  const size_t O_NT     = O_DIR + 1280;                             // 16
  const size_t O_GATES  = O_NT + 16;                                // B*10*4
  const size_t O_COMMON = O_GATES + (size_t)B_SZ * 10 * 4;          // B*U*2
  const size_t O_FOUT   = O_COMMON + (size_t)B_SZ * U_SZ * 2;       // B*F*U*2
  const size_t O_RINFO  = O_FOUT + (size_t)B_SZ * F_SZ * U_SZ * 2;  // B*4
  const size_t O_BHIST  = O_RINFO + (size_t)B_SZ * 4;               // 32*64*4

  ushort_t* xbf     = (ushort_t*)(ws + O_XBF);
  ushort_t* wbf     = (ushort_t*)(ws + O_WBF);
  ushort_t* wgbf    = (ushort_t*)(ws + O_WGBF);
  unsigned int* patp= (unsigned int*)(ws + O_PAT);
  int*      rowidxp = (int*)(ws + O_ROWIDX);
  int*      cntp    = (int*)(ws + O_CNT);
  int*      dirp    = (int*)(ws + O_DIR);
  int*      ntp     = (int*)(ws + O_NT);
  float*    gatesp  = (float*)(ws + O_GATES);
  ushort_t* commonp = (ushort_t*)(ws + O_COMMON);
  ushort_t* foutp   = (ushort_t*)(ws + O_FOUT);
  unsigned int* rinfop = (unsigned int*)(ws + O_RINFO);
  int*      bhistp  = (int*)(ws + O_BHIST);

  prep_k<<<dim3(6305), dim3(256), 0, stream>>>(x, Wc, We, Wg, xbf, wbf, wgbf,
                                               patp, rinfop, bhistp);
  scanscat_k<<<dim3(1), dim3(1024), 0, stream>>>(bhistp, patp, rinfop,
                                                 rowidxp, cntp, dirp, ntp);
  gemm2<<<dim3(1792), dim3(256), 0, stream>>>(xbf, wbf, wgbf, bg, rowidxp, cntp,
                                              dirp, ntp, bc, be, commonp, foutp,
                                              gatesp);
  stage2_k<<<dim3(2048), dim3(256), 0, stream>>>(commonp, foutp, patp, gatesp,
                                                 Wa, ba, Wu, bu, out);
}

// Round 7
// 277.929 us; speedup vs baseline: 1.6935x; 1.0124x over previous
//
#include <hip/hip_runtime.h>

typedef unsigned short ushort_t;

#define B_SZ 8192
#define D_SZ 1024
#define U_SZ 512
#define F_SZ 4
#define E_SZ 4
#define T_SZ 2

typedef __attribute__((ext_vector_type(8))) short bf16x8;     // 8 bf16 = 4 VGPRs (MFMA A/B frag)
typedef __attribute__((ext_vector_type(4))) float f32x4;      // MFMA C/D frag
typedef __attribute__((ext_vector_type(8))) unsigned short u16x8;

__device__ __forceinline__ unsigned short f2bf(float f) {
  union { float f; unsigned int u; } v; v.f = f;
  unsigned int r = v.u + 0x7FFFu + ((v.u >> 16) & 1u);  // RNE; inputs are finite normals
  return (unsigned short)(r >> 16);
}
__device__ __forceinline__ float bf2f(unsigned short h) {
  union { unsigned int u; float f; } v; v.u = ((unsigned int)h) << 16;
  return v.f;
}
__device__ __forceinline__ float bfu_lo(unsigned int u) {   // low 16 bits as bf16->f32
  union { unsigned int u; float f; } v; v.u = u << 16; return v.f;
}
__device__ __forceinline__ float bfu_hi(unsigned int u) {   // high 16 bits as bf16->f32
  union { unsigned int u; float f; } v; v.u = u & 0xFFFF0000u; return v.f;
}

// async global->LDS, 16B per lane; LDS dest = wave-uniform base + lane*16
__device__ __forceinline__ void gload_lds16(const void* g, void* l) {
  __builtin_amdgcn_global_load_lds(
      (const __attribute__((address_space(1))) unsigned int*)g,
      (__attribute__((address_space(3))) unsigned int*)l, 16, 0, 0);
}

// ============ prep: conv_x | conv_w | Wg-transpose | patterns ============
__global__ __launch_bounds__(256) void prep_k(
    const float* __restrict__ x, const float* __restrict__ Wc,
    const float* __restrict__ We, const float* __restrict__ Wg,
    ushort_t* __restrict__ xbf, ushort_t* __restrict__ wbf,
    ushort_t* __restrict__ wgbf, unsigned int* __restrict__ pat,
    unsigned int* __restrict__ rowinfo, int* __restrict__ blockhist) {
  __shared__ __align__(16) char smem[17664];
  const int bid = blockIdx.x;
  const int t = threadIdx.x;

  if (bid < 4096) {
    const size_t i = ((size_t)bid * 256 + t) * 8;
    const float4 a = *(const float4*)(x + i);
    const float4 c = *(const float4*)(x + i + 4);
    u16x8 o;
    o[0] = f2bf(a.x); o[1] = f2bf(a.y); o[2] = f2bf(a.z); o[3] = f2bf(a.w);
    o[4] = f2bf(c.x); o[5] = f2bf(c.y); o[6] = f2bf(c.z); o[7] = f2bf(c.w);
    *(u16x8*)(xbf + i) = o;
  } else if (bid < 6272) {
    const int blk = bid - 4096;
    const int midx = blk >> 7;
    const int tid = blk & 127;
    const int trow = (tid >> 3) * 64;
    const int tcol = (tid & 7) * 64;
    const float* src = (midx == 0) ? Wc : (We + (size_t)(midx - 1) * D_SZ * U_SZ);
    ushort_t* dst = wbf + (size_t)midx * U_SZ * D_SZ;
    float (*tile)[69] = (float(*)[69])smem;
    const int r0 = t >> 2;
    const int cseg = (t & 3) * 16;
#pragma unroll
    for (int j = 0; j < 4; ++j) {
      const float4 v = *(const float4*)(src + (size_t)(trow + r0) * U_SZ + tcol + cseg + j * 4);
      tile[r0][cseg + j * 4 + 0] = v.x;
      tile[r0][cseg + j * 4 + 1] = v.y;
      tile[r0][cseg + j * 4 + 2] = v.z;
      tile[r0][cseg + j * 4 + 3] = v.w;
    }
    __syncthreads();
    const int u = t >> 2;
    const int d0 = (t & 3) * 16;
#pragma unroll
    for (int h = 0; h < 2; ++h) {
      u16x8 ov;
#pragma unroll
      for (int k = 0; k < 8; ++k) ov[k] = f2bf(tile[d0 + h * 8 + k][u]);
      *(u16x8*)(dst + (size_t)(tcol + u) * D_SZ + trow + d0 + h * 8) = ov;
    }
  } else if (bid == 6272) {
#pragma unroll
    for (int j = 0; j < 40; ++j) {
      const int i = j * 256 + t;
      const int t2 = i / 5120;
      const int rem = i - t2 * 5120;
      const int d = rem / 5;
      const int g = rem - d * 5;
      wgbf[(t2 * 5 + g) * 1024 + d] = f2bf(Wg[i]);
    }
#pragma unroll
    for (int j = 0; j < 24; ++j)
      wgbf[10 * 1024 + j * 256 + t] = 0;
  } else {
    const int pb = bid - 6273;
    int* hist = (int*)smem;
    if (t < 64) hist[t] = 0;
    __syncthreads();
    const int b = pb * 256 + t;
    const float4 a = *(const float4*)(x + (size_t)b * D_SZ);
    const float4 c = *(const float4*)(x + (size_t)b * D_SZ + 4);
    const float v0 = x[(size_t)b * D_SZ + 8];
    const float v1 = x[(size_t)b * D_SZ + 9];
    int pp[4];
    pp[0] = (int)(a.x > 0.f) | ((int)(a.y > 0.f) << 1) |
            ((int)(a.z > 0.f) << 2) | ((int)(a.w > 0.f) << 3);
    pp[1] = (int)(c.x > 0.f) | ((int)(c.y > 0.f) << 1) |
            ((int)(c.z > 0.f) << 2) | ((int)(c.w > 0.f) << 3);
    const float LO[4] = {-1e10f, -0.5f, 0.f, 0.5f};
    const float HI[4] = {-0.5f, 0.f, 0.5f, 1e10f};
    pp[2] = 0; pp[3] = 0;
#pragma unroll
    for (int j = 0; j < 4; ++j) {
      if ((v0 > LO[j]) && (v0 <= HI[j])) pp[2] = 1 << j;
      if ((v1 > LO[j]) && (v1 <= HI[j])) pp[3] = 1 << j;
    }
    pat[b] = (unsigned int)(pp[0] | (pp[1] << 4) | (pp[2] << 8) | (pp[3] << 12));
    unsigned int info = 0;
#pragma unroll
    for (int f = 0; f < 4; ++f) {
      if (pp[f]) {
        const int lp = atomicAdd(&hist[f * 16 + pp[f]], 1);
        info |= (unsigned int)lp << (8 * f);
      }
    }
    rowinfo[b] = info;
    __syncthreads();
    if (t < 64) blockhist[pb * 64 + t] = hist[t];
  }
}

// ===== scan histograms + directory + scatter (1 block, LDS-resident) =====
__global__ __launch_bounds__(1024) void scanscat_k(
    const int* __restrict__ blockhist, const unsigned int* __restrict__ pat,
    const unsigned int* __restrict__ rowinfo,
    int* __restrict__ rowidx, int* __restrict__ cnt,
    int* __restrict__ dir, int* __restrict__ ntiles) {
  __shared__ int shist[32 * 64];
  __shared__ int scnt[64];
  const int t = threadIdx.x;
  shist[t] = blockhist[t];
  shist[t + 1024] = blockhist[t + 1024];
  __syncthreads();
  if (t < 64) {
    int run = 0;
    for (int blk = 0; blk < 32; ++blk) {
      const int v = shist[blk * 64 + t];
      shist[blk * 64 + t] = run;
      run += v;
    }
    scnt[t] = run;
    cnt[t] = run;
  }
  __syncthreads();
  if (t < 4) {
    const int f = t;
    int idx = 0;
    for (int pop = 4; pop >= 1; --pop) {
      for (int p = 1; p < 16; ++p) {
        if (__popc(p) != pop) continue;
        const int n = scnt[f * 16 + p];
        const int nt = (n + 127) >> 7;
        for (int k = 0; k < nt; ++k) dir[f * 80 + idx++] = p | (k << 8);
      }
    }
    ntiles[f] = idx;
  }
#pragma unroll
  for (int it = 0; it < 8; ++it) {
    const int b = it * 1024 + t;
    const unsigned int pv = pat[b];
    const unsigned int info = rowinfo[b];
    const int blk = b >> 8;
#pragma unroll
    for (int f = 0; f < 4; ++f) {
      const int p = (int)((pv >> (4 * f)) & 15u);
      if (p) {
        const int pos = shist[blk * 64 + f * 16 + p] + (int)((info >> (8 * f)) & 255u);
        rowidx[((size_t)(f * 16 + p)) * B_SZ + pos] = b;
      }
    }
  }
}

// ================= pattern-grouped gathered bf16 MFMA GEMM + gates =================
// 1D grid, uc fastest (siblings co-resident, A L2-shared). facc packed as bf16
// pairs (32 regs, frees AGPR budget) -> LB(256,3) targets 3 blocks/CU.
__global__ __launch_bounds__(256, 3) void gemm2(
    const ushort_t* __restrict__ xbf, const ushort_t* __restrict__ wbf,
    const ushort_t* __restrict__ wgbf, const float* __restrict__ bg,
    const int* __restrict__ rowidx, const int* __restrict__ cnt,
    const int* __restrict__ dir, const int* __restrict__ ntiles,
    const float* __restrict__ bc, const float* __restrict__ be,
    ushort_t* __restrict__ common, ushort_t* __restrict__ fout,
    float* __restrict__ gates) {
  __shared__ ushort_t Ash[128 * 64];
  __shared__ ushort_t Bsh[128 * 64];
  __shared__ int ridx[128];

  const int t = threadIdx.x;
  const int lane = t & 63;
  const int w = t >> 6;
  const int wm = w >> 1;
  const int wn = w & 1;
  const int quad = lane >> 4;
  const int l16 = lane & 15;

  const int id = blockIdx.x;
  const int uc = id & 3;
  const int s = id >> 2;
  int g, slot;
  if (s < 320) { g = s / 80; slot = s - g * 80; }
  else if (s < 384) { g = 4; slot = s - 320; }
  else { g = 5; slot = s - 384; }
  const int u0 = uc * 128;

  // ---------------- gates GEMM branch ----------------
  if (g == 5) {
    if (uc != 0) return;
    if (t < 128) ridx[t] = slot * 128 + t;
    __syncthreads();
    size_t aoff[4]; int aldso[4];
#pragma unroll
    for (int i = 0; i < 4; ++i) {
      const int c = (w * 4 + i) * 64 + lane;
      const int r = c >> 3;
      const int gc = (c & 7) ^ (r & 7);
      aoff[i] = (size_t)ridx[r] * D_SZ + gc * 8;
      aldso[i] = (w * 4 + i) * 1024;
    }
    int bo = 0, bldso = 0;
    if (w < 2) {
      const int c = w * 64 + lane;
      const int r = c >> 3;
      const int gc = (c & 7) ^ (r & 7);
      bo = r * D_SZ + gc * 8;
      bldso = w * 1024;
    }
    int sw[2];
    sw[0] = ((quad) ^ (l16 & 7)) * 8;
    sw[1] = ((4 + quad) ^ (l16 & 7)) * 8;
    const f32x4 fzero = {0.f, 0.f, 0.f, 0.f};
    f32x4 acc[2];
    acc[0] = fzero; acc[1] = fzero;
    for (int k0 = 0; k0 < D_SZ; k0 += 64) {
#pragma unroll
      for (int i = 0; i < 4; ++i)
        gload_lds16(xbf + aoff[i] + k0, (char*)Ash + aldso[i]);
      if (w < 2) gload_lds16(wgbf + bo + k0, (char*)Bsh + bldso);
      __syncthreads();
#pragma unroll
      for (int qs = 0; qs < 2; ++qs) {
        const bf16x8 bv = *(const bf16x8*)(Bsh + l16 * 64 + sw[qs]);
#pragma unroll
        for (int i = 0; i < 2; ++i) {
          const bf16x8 av = *(const bf16x8*)(Ash + (w * 32 + i * 16 + l16) * 64 + sw[qs]);
          acc[i] = __builtin_amdgcn_mfma_f32_16x16x32_bf16(av, bv, acc[i], 0, 0, 0);
        }
      }
      __syncthreads();
    }
    float* lsc = (float*)Ash;          // 128 x 17 logits (pad 17: no bank conflicts)
#pragma unroll
    for (int i = 0; i < 2; ++i)
#pragma unroll
      for (int r = 0; r < 4; ++r)
        lsc[(w * 32 + i * 16 + quad * 4 + r) * 17 + l16] = acc[i][r];
    __syncthreads();
    if (t < 128) {
      const int b = slot * 128 + t;
      float l[10];
#pragma unroll
      for (int k = 0; k < 10; ++k) l[k] = lsc[t * 17 + k] + bg[k];
      const float mx0 = fmaxf(fmaxf(fmaxf(l[0], l[1]), fmaxf(l[2], l[3])), l[4]);
      const float mx1 = fmaxf(fmaxf(fmaxf(l[5], l[6]), fmaxf(l[7], l[8])), l[9]);
      float ev[10]; float s0 = 0.f, s1 = 0.f;
#pragma unroll
      for (int k = 0; k < 5; ++k) { ev[k] = expf(l[k] - mx0); s0 += ev[k]; }
#pragma unroll
      for (int k = 5; k < 10; ++k) { ev[k] = expf(l[k] - mx1); s1 += ev[k]; }
      const float r0 = 1.f / s0, r1 = 1.f / s1;
#pragma unroll
      for (int k = 0; k < 5; ++k) gates[(size_t)b * 10 + k] = ev[k] * r0;
#pragma unroll
      for (int k = 5; k < 10; ++k) gates[(size_t)b * 10 + k] = ev[k] * r1;
    }
    return;
  }

  // ---------------- expert GEMM (field / common) ----------------
  const bool isCommon = (g == 4);
  int p = 0, nrows = 128;
  if (isCommon) {
    if (t < 128) ridx[t] = slot * 128 + t;
  } else {
    if (slot >= ntiles[g]) return;
    const int entry = dir[g * 80 + slot];
    p = entry & 15;
    const int tw = entry >> 8;
    const int n = cnt[g * 16 + p];
    const int rbase = tw * 128;
    nrows = min(128, n - rbase);
    if (t < 128) {
      const int rr = rbase + ((t < nrows) ? t : 0);
      ridx[t] = rowidx[((size_t)g * 16 + p) * B_SZ + rr];
    }
  }
  __syncthreads();

  size_t aoff[4]; int boff[4]; int ldso[4];
#pragma unroll
  for (int i = 0; i < 4; ++i) {
    const int c = (w * 4 + i) * 64 + lane;
    const int r = c >> 3;
    const int gc = (c & 7) ^ (r & 7);
    aoff[i] = (size_t)ridx[r] * D_SZ + gc * 8;
    boff[i] = r * D_SZ + gc * 8;
    ldso[i] = (w * 4 + i) * 1024;
  }
  int rowA[4], rowB[4];
#pragma unroll
  for (int i = 0; i < 4; ++i) {
    rowA[i] = wm * 64 + i * 16 + l16;
    rowB[i] = wn * 64 + i * 16 + l16;
  }
  int sw[2];
  sw[0] = ((quad) ^ (l16 & 7)) * 8;
  sw[1] = ((4 + quad) ^ (l16 & 7)) * 8;

  int elist[4]; int ne = 0;
  if (isCommon) { elist[0] = 0; ne = 1; }
  else {
#pragma unroll
    for (int e = 0; e < 4; ++e)
      if (p & (1 << e)) elist[ne++] = e;
  }

  const f32x4 fzero = {0.f, 0.f, 0.f, 0.f};
  // facc packed: 2 bf16 per u32, elements (r=2j, r=2j+1) -> 32 regs total
  unsigned int fpk[4][4][2];
#pragma unroll
  for (int mi = 0; mi < 4; ++mi)
#pragma unroll
    for (int ni = 0; ni < 4; ++ni) { fpk[mi][ni][0] = 0u; fpk[mi][ni][1] = 0u; }

  for (int ei = 0; ei < ne; ++ei) {
    const int midx = isCommon ? 0 : (1 + g * 4 + elist[ei]);
    const ushort_t* wbase = wbf + (size_t)midx * (U_SZ * D_SZ) + (size_t)u0 * D_SZ;
    f32x4 acc[4][4];
#pragma unroll
    for (int mi = 0; mi < 4; ++mi)
#pragma unroll
      for (int ni = 0; ni < 4; ++ni) acc[mi][ni] = fzero;

    for (int k0 = 0; k0 < D_SZ; k0 += 64) {
#pragma unroll
      for (int i = 0; i < 4; ++i) {
        gload_lds16(xbf + aoff[i] + k0, (char*)Ash + ldso[i]);
        gload_lds16(wbase + boff[i] + k0, (char*)Bsh + ldso[i]);
      }
      __syncthreads();
#pragma unroll
      for (int qs = 0; qs < 2; ++qs) {
        bf16x8 av[4], bv[4];
#pragma unroll
        for (int mi = 0; mi < 4; ++mi)
          av[mi] = *(const bf16x8*)(Ash + rowA[mi] * 64 + sw[qs]);
#pragma unroll
        for (int ni = 0; ni < 4; ++ni)
          bv[ni] = *(const bf16x8*)(Bsh + rowB[ni] * 64 + sw[qs]);
#pragma unroll
        for (int mi = 0; mi < 4; ++mi)
#pragma unroll
          for (int ni = 0; ni < 4; ++ni)
            acc[mi][ni] = __builtin_amdgcn_mfma_f32_16x16x32_bf16(av[mi], bv[ni],
                                                                  acc[mi][ni], 0, 0, 0);
      }
      __syncthreads();
    }

    if (isCommon) {
#pragma unroll
      for (int mi = 0; mi < 4; ++mi) {
        const int rowb = slot * 128 + wm * 64 + mi * 16 + quad * 4;
#pragma unroll
        for (int ni = 0; ni < 4; ++ni) {
          const int u = u0 + wn * 64 + ni * 16 + l16;
          const float bcv = bc[u];
#pragma unroll
          for (int r = 0; r < 4; ++r) {
            const float v = fmaxf(acc[mi][ni][r] + bcv, 0.f);
            common[(size_t)(rowb + r) * U_SZ + u] = f2bf(v);
          }
        }
      }
    } else {
      const float* bevp = be + (size_t)(g * 4 + elist[ei]) * U_SZ;
#pragma unroll
      for (int ni = 0; ni < 4; ++ni) {
        const int u = u0 + wn * 64 + ni * 16 + l16;
        const float bev = bevp[u];
#pragma unroll
        for (int mi = 0; mi < 4; ++mi) {
#pragma unroll
          for (int j = 0; j < 2; ++j) {
            const float v0 = fmaxf(acc[mi][ni][2 * j] + bev, 0.f);
            const float v1 = fmaxf(acc[mi][ni][2 * j + 1] + bev, 0.f);
            const unsigned int old = fpk[mi][ni][j];
            const float s0 = bfu_lo(old) + v0;
            const float s1 = bfu_hi(old) + v1;
            fpk[mi][ni][j] = (unsigned int)f2bf(s0) | ((unsigned int)f2bf(s1) << 16);
          }
        }
      }
    }
  }

  if (!isCommon) {
#pragma unroll
    for (int mi = 0; mi < 4; ++mi) {
      const int rowl = wm * 64 + mi * 16 + quad * 4;
#pragma unroll
      for (int r = 0; r < 4; ++r) {
        if (rowl + r < nrows) {
          const int brow = ridx[rowl + r];
#pragma unroll
          for (int ni = 0; ni < 4; ++ni) {
            const int u = u0 + wn * 64 + ni * 16 + l16;
            const unsigned int pk = fpk[mi][ni][r >> 1];
            const ushort_t hv = (r & 1) ? (ushort_t)(pk >> 16) : (ushort_t)(pk & 0xFFFFu);
            fout[((size_t)brow * F_SZ + g) * U_SZ + u] = hv;   // already bf16
          }
        }
      }
    }
  }
}

// ---------------- stage 2: one wave per row ----------------
__global__ __launch_bounds__(256) void stage2_k(
    const ushort_t* __restrict__ common, const ushort_t* __restrict__ fout,
    const unsigned int* __restrict__ pat, const float* __restrict__ gates,
    const float* __restrict__ Wa, const float* __restrict__ ba,
    const float* __restrict__ Wu, const float* __restrict__ bu,
    float* __restrict__ out) {
  const int t = threadIdx.x;
  const int lane = t & 63;
  const int w = t >> 6;
  const int b = blockIdx.x * 4 + w;
  const int ub = lane * 8;
  const unsigned int pv = pat[b];

  float cf[8];
  {
    const u16x8 cv = *(const u16x8*)(common + (size_t)b * U_SZ + ub);
#pragma unroll
    for (int j = 0; j < 8; ++j) cf[j] = bf2f(cv[j]);
  }
  float fo[4][8];
#pragma unroll
  for (int f = 0; f < 4; ++f) {
    const bool act = ((pv >> (4 * f)) & 15u) != 0u;
    const u16x8 fv = *(const u16x8*)(fout + ((size_t)b * F_SZ + f) * U_SZ + ub);
#pragma unroll
    for (int j = 0; j < 8; ++j) fo[f][j] = act ? bf2f(fv[j]) : 0.f;
  }
  float pa[4], pu[4];
#pragma unroll
  for (int f = 0; f < 4; ++f) {
    const float* wa = Wa + f * 1024;
    const float* wu = Wu + f * 1024;
    const float4 a0 = *(const float4*)(wa + ub);
    const float4 a1 = *(const float4*)(wa + ub + 4);
    const float4 a2 = *(const float4*)(wa + 512 + ub);
    const float4 a3 = *(const float4*)(wa + 512 + ub + 4);
    const float4 u0v = *(const float4*)(wu + ub);
    const float4 u1v = *(const float4*)(wu + ub + 4);
    const float4 u2v = *(const float4*)(wu + 512 + ub);
    const float4 u3v = *(const float4*)(wu + 512 + ub + 4);
    pa[f] = cf[0]*a0.x + cf[1]*a0.y + cf[2]*a0.z + cf[3]*a0.w
          + cf[4]*a1.x + cf[5]*a1.y + cf[6]*a1.z + cf[7]*a1.w
          + fo[f][0]*a2.x + fo[f][1]*a2.y + fo[f][2]*a2.z + fo[f][3]*a2.w
          + fo[f][4]*a3.x + fo[f][5]*a3.y + fo[f][6]*a3.z + fo[f][7]*a3.w;
    pu[f] = cf[0]*u0v.x + cf[1]*u0v.y + cf[2]*u0v.z + cf[3]*u0v.w
          + cf[4]*u1v.x + cf[5]*u1v.y + cf[6]*u1v.z + cf[7]*u1v.w
          + fo[f][0]*u2v.x + fo[f][1]*u2v.y + fo[f][2]*u2v.z + fo[f][3]*u2v.w
          + fo[f][4]*u3v.x + fo[f][5]*u3v.y + fo[f][6]*u3v.z + fo[f][7]*u3v.w;
  }
#pragma unroll
  for (int off = 32; off > 0; off >>= 1) {
#pragma unroll
    for (int f = 0; f < 4; ++f) {
      pa[f] += __shfl_xor(pa[f], off);
      pu[f] += __shfl_xor(pu[f], off);
    }
  }
  float gg[10];
#pragma unroll
  for (int k = 0; k < 10; ++k) gg[k] = gates[(size_t)b * 10 + k];
  float o0[8], o1[8];
#pragma unroll
  for (int j = 0; j < 8; ++j) { o0[j] = gg[0] * cf[j]; o1[j] = gg[5] * cf[j]; }
#pragma unroll
  for (int f = 0; f < 4; ++f) {
    const float att = 1.f / (1.f + expf(-(pa[f] + ba[f])));
    const float upd = 1.f / (1.f + expf(-(pu[f] + bu[f])));
    const float au = att * upd, cu = 1.f - upd;
#pragma unroll
    for (int j = 0; j < 8; ++j) {
      const float ff = au * fo[f][j] + cu * cf[j];
      o0[j] += gg[1 + f] * ff;
      o1[j] += gg[6 + f] * ff;
    }
  }
  float* op0 = out + ((size_t)b * T_SZ + 0) * U_SZ + ub;
  float* op1 = out + ((size_t)b * T_SZ + 1) * U_SZ + ub;
  *(float4*)(op0)     = make_float4(o0[0], o0[1], o0[2], o0[3]);
  *(float4*)(op0 + 4) = make_float4(o0[4], o0[5], o0[6], o0[7]);
  *(float4*)(op1)     = make_float4(o1[0], o1[1], o1[2], o1[3]);
  *(float4*)(op1 + 4) = make_float4(o1[4], o1[5], o1[6], o1[7]);
}

// ---------------- launch ----------------
extern "C" void kernel_launch(void* const* d_in, const int* in_sizes, int n_in,
                              void* d_out, int out_size, void* d_ws, size_t ws_size,
                              hipStream_t stream) {
  (void)in_sizes; (void)n_in; (void)out_size; (void)ws_size;
  const float* x  = (const float*)d_in[0];
  const float* Wc = (const float*)d_in[1];
  const float* bc = (const float*)d_in[2];
  const float* We = (const float*)d_in[3];
  const float* be = (const float*)d_in[4];
  const float* Wg = (const float*)d_in[5];
  const float* bg = (const float*)d_in[6];
  const float* Wa = (const float*)d_in[7];
  const float* ba = (const float*)d_in[8];
  const float* Wu = (const float*)d_in[9];
  const float* bu = (const float*)d_in[10];
  float* out = (float*)d_out;
  char* ws = (char*)d_ws;

  const size_t O_XBF    = 0;                                        // B*D*2
  const size_t O_WBF    = O_XBF + (size_t)B_SZ * D_SZ * 2;          // 17*U*D*2
  const size_t O_WGBF   = O_WBF + (size_t)17 * U_SZ * D_SZ * 2;     // 16*1024*2
  const size_t O_PAT    = O_WGBF + 16 * 1024 * 2;                   // B*4
  const size_t O_ROWIDX = O_PAT + (size_t)B_SZ * 4;                 // 4*16*B*4
  const size_t O_CNT    = O_ROWIDX + (size_t)4 * 16 * B_SZ * 4;     // 64*4
  const size_t O_DIR    = O_CNT + 256;                              // 4*80*4
  const size_t O_NT     = O_DIR + 1280;                             // 16
  const size_t O_GATES  = O_NT + 16;                                // B*10*4
  const size_t O_COMMON = O_GATES + (size_t)B_SZ * 10 * 4;          // B*U*2
  const size_t O_FOUT   = O_COMMON + (size_t)B_SZ * U_SZ * 2;       // B*F*U*2
  const size_t O_RINFO  = O_FOUT + (size_t)B_SZ * F_SZ * U_SZ * 2;  // B*4
  const size_t O_BHIST  = O_RINFO + (size_t)B_SZ * 4;               // 32*64*4

  ushort_t* xbf     = (ushort_t*)(ws + O_XBF);
  ushort_t* wbf     = (ushort_t*)(ws + O_WBF);
  ushort_t* wgbf    = (ushort_t*)(ws + O_WGBF);
  unsigned int* patp= (unsigned int*)(ws + O_PAT);
  int*      rowidxp = (int*)(ws + O_ROWIDX);
  int*      cntp    = (int*)(ws + O_CNT);
  int*      dirp    = (int*)(ws + O_DIR);
  int*      ntp     = (int*)(ws + O_NT);
  float*    gatesp  = (float*)(ws + O_GATES);
  ushort_t* commonp = (ushort_t*)(ws + O_COMMON);
  ushort_t* foutp   = (ushort_t*)(ws + O_FOUT);
  unsigned int* rinfop = (unsigned int*)(ws + O_RINFO);
  int*      bhistp  = (int*)(ws + O_BHIST);

  prep_k<<<dim3(6305), dim3(256), 0, stream>>>(x, Wc, We, Wg, xbf, wbf, wgbf,
                                               patp, rinfop, bhistp);
  scanscat_k<<<dim3(1), dim3(1024), 0, stream>>>(bhistp, patp, rinfop,
                                                 rowidxp, cntp, dirp, ntp);
  gemm2<<<dim3(1792), dim3(256), 0, stream>>>(xbf, wbf, wgbf, bg, rowidxp, cntp,
                                              dirp, ntp, bc, be, commonp, foutp,
                                              gatesp);
  stage2_k<<<dim3(2048), dim3(256), 0, stream>>>(commonp, foutp, patp, gatesp,
                                                 Wa, ba, Wu, bu, out);
}